// Round 1
// baseline (20818.031 us; speedup 1.0000x reference)
//
#include <hip/hip_runtime.h>

#define N_NODES 100000
#define E_EDGES 1600000
#define IN_F 128
#define H_F 256
#define K_HOPS 7
#define R_REL 5
#define OUT_W (R_REL * H_F)  // 1280

// ---------------- small utility kernels ----------------

__global__ void zero_int(int* __restrict__ p, int n) {
    int t = blockIdx.x * blockDim.x + threadIdx.x;
    if (t < n) p[t] = 0;
}

__global__ void deg_count(const int* __restrict__ row, int* __restrict__ deg) {
    int e = blockIdx.x * blockDim.x + threadIdx.x;
    if (e < E_EDGES) atomicAdd(&deg[row[e]], 1);
}

__global__ void dinv_compute(const int* __restrict__ deg, float* __restrict__ dinv) {
    int i = blockIdx.x * blockDim.x + threadIdx.x;
    if (i < N_NODES) dinv[i] = rsqrtf((float)(deg[i] + 1));  // +1 self loop; always > 0
}

__global__ void edge_weights(const int* __restrict__ row, const int* __restrict__ col,
                             const float* __restrict__ dinv, float* __restrict__ ew) {
    int e = blockIdx.x * blockDim.x + threadIdx.x;
    if (e < E_EDGES) ew[e] = dinv[row[e]] * dinv[col[e]];
}

// y = dinv^2 * x   (self-loop term, full overwrite => no zeroing needed)
__global__ void spmm_init(const float4* __restrict__ x, const float* __restrict__ dinv,
                          float4* __restrict__ y) {
    int t = blockIdx.x * blockDim.x + threadIdx.x;
    if (t < N_NODES * (IN_F / 4)) {
        int i = t >> 5;  // 32 float4 per row
        float d = dinv[i];
        float s = d * d;
        float4 v = x[t];
        v.x *= s; v.y *= s; v.z *= s; v.w *= s;
        y[t] = v;
    }
}

// y[row[e]] += w[e] * x[col[e]]  (one float4 lane-slice per thread, 32 threads/edge)
__global__ void spmm_edges(const float4* __restrict__ x, const float* __restrict__ ew,
                           const int* __restrict__ row, const int* __restrict__ col,
                           float* __restrict__ y) {
    int t = blockIdx.x * blockDim.x + threadIdx.x;
    if (t >= E_EDGES * (IN_F / 4)) return;
    int e = t >> 5, q = t & 31;
    int r = row[e], c = col[e];
    float w = ew[e];
    float4 v = x[(long)c * (IN_F / 4) + q];
    float* dst = y + (long)r * IN_F + q * 4;
    unsafeAtomicAdd(dst + 0, w * v.x);
    unsafeAtomicAdd(dst + 1, w * v.y);
    unsafeAtomicAdd(dst + 2, w * v.z);
    unsafeAtomicAdd(dst + 3, w * v.w);
}

// ---------------- fp32 tiled GEMM ----------------
// C[M,256] (+)= A[M,K] @ B[K,256] (+ bias) (+ relu)
// BM=128, BN=64, BK=16; 256 threads; 8x4 micro-tile per thread.

#define BM 128
#define BN 64
#define BK 16

template <bool ACCUM, bool BIAS, bool RELU>
__global__ __launch_bounds__(256) void gemm_f32(
    const float* __restrict__ A, int lda,
    const float* __restrict__ B, int ldb,
    float* __restrict__ C, int ldc,
    const float* __restrict__ bias,
    int M, int K)
{
    __shared__ float As[BK][BM];  // transposed: As[k][m]
    __shared__ float Bs[BK][BN];

    const int tid = threadIdx.x;
    const int tx = tid & 15;   // col group (4 cols)
    const int ty = tid >> 4;   // row group (8 rows)
    const int m0 = blockIdx.y * BM;
    const int n0 = blockIdx.x * BN;

    float acc[8][4];
#pragma unroll
    for (int i = 0; i < 8; ++i)
#pragma unroll
        for (int j = 0; j < 4; ++j) acc[i][j] = 0.f;

    for (int k0 = 0; k0 < K; k0 += BK) {
        // A tile: 128x16 = 512 float4, 2 per thread, store transposed
#pragma unroll
        for (int l = 0; l < 2; ++l) {
            int fid = tid + l * 256;
            int r = fid >> 2, c4 = fid & 3;
            float4 v = make_float4(0.f, 0.f, 0.f, 0.f);
            int m = m0 + r;
            if (m < M) v = *(const float4*)(A + (long)m * lda + k0 + c4 * 4);
            As[c4 * 4 + 0][r] = v.x;
            As[c4 * 4 + 1][r] = v.y;
            As[c4 * 4 + 2][r] = v.z;
            As[c4 * 4 + 3][r] = v.w;
        }
        // B tile: 16x64 = 256 float4, 1 per thread
        {
            int r = tid >> 4, c4 = tid & 15;
            float4 v = *(const float4*)(B + (long)(k0 + r) * ldb + n0 + c4 * 4);
            *(float4*)&Bs[r][c4 * 4] = v;
        }
        __syncthreads();
#pragma unroll
        for (int kk = 0; kk < BK; ++kk) {
            float4 b4 = *(const float4*)&Bs[kk][tx * 4];
            float4 a0 = *(const float4*)&As[kk][ty * 8];
            float4 a1 = *(const float4*)&As[kk][ty * 8 + 4];
            float a[8] = {a0.x, a0.y, a0.z, a0.w, a1.x, a1.y, a1.z, a1.w};
            float b[4] = {b4.x, b4.y, b4.z, b4.w};
#pragma unroll
            for (int i = 0; i < 8; ++i)
#pragma unroll
                for (int j = 0; j < 4; ++j)
                    acc[i][j] = fmaf(a[i], b[j], acc[i][j]);
        }
        __syncthreads();
    }

#pragma unroll
    for (int i = 0; i < 8; ++i) {
        int m = m0 + ty * 8 + i;
        if (m < M) {
            float* cp = C + (long)m * ldc + n0 + tx * 4;
#pragma unroll
            for (int j = 0; j < 4; ++j) {
                float v = acc[i][j];
                if (BIAS) v += bias[n0 + tx * 4 + j];
                if (ACCUM) v += cp[j];
                if (RELU) v = fmaxf(v, 0.f);
                cp[j] = v;
            }
        }
    }
}

template <bool ACC, bool BI, bool RE>
static void launch_gemm(const float* A, int lda, const float* B, int ldb,
                        float* C, int ldc, const float* bias, int M, int K,
                        hipStream_t s) {
    dim3 grid(H_F / BN, (M + BM - 1) / BM);  // N is always 256 wide here
    gemm_f32<ACC, BI, RE><<<grid, 256, 0, s>>>(A, lda, B, ldb, C, ldc, bias, M, K);
}

// ---------------- driver ----------------

extern "C" void kernel_launch(void* const* d_in, const int* in_sizes, int n_in,
                              void* d_out, int out_size, void* d_ws, size_t ws_size,
                              hipStream_t stream) {
    const float* features = (const float*)d_in[0];
    const float* W1 = (const float*)d_in[1];
    const float* b1 = (const float*)d_in[2];
    const float* W2 = (const float*)d_in[3];
    const float* b2 = (const float*)d_in[4];
    const float* Wr = (const float*)d_in[5];
    const float* br = (const float*)d_in[6];
    const int* row = (const int*)d_in[7];
    const int* col = (const int*)d_in[8];
    float* out = (float*)d_out;

    // workspace layout
    char* ws = (char*)d_ws;
    int* deg = (int*)ws;                                   // N ints
    float* dinv = (float*)(ws + (1 << 20));                // N floats
    float* ew = dinv + 1024 * 1024 / 4;                    // E floats (offset +1MB)
    float* xa = ew + 2 * 1024 * 1024;                      // N*128
    float* xb = xa + (size_t)N_NODES * IN_F;
    float* h1 = xb + (size_t)N_NODES * IN_F;               // N*256
    float* h2 = h1 + (size_t)N_NODES * H_F;                // N*256

    // ---- adjacency normalization ----
    zero_int<<<(N_NODES + 255) / 256, 256, 0, stream>>>(deg, N_NODES);
    deg_count<<<(E_EDGES + 255) / 256, 256, 0, stream>>>(row, deg);
    dinv_compute<<<(N_NODES + 255) / 256, 256, 0, stream>>>(deg, dinv);
    edge_weights<<<(E_EDGES + 255) / 256, 256, 0, stream>>>(row, col, dinv, ew);

    // ---- hop loop: MLP(k) -> accumulate into relation windows; then propagate ----
    const float* xcur = features;
    float* bufs[2] = {xa, xb};
    for (int k = 0; k < K_HOPS; ++k) {
        // MLP layer 1: h1 = relu(x @ W1[k] + b1[k])
        launch_gemm<false, true, true>(xcur, IN_F, W1 + (size_t)k * IN_F * H_F, H_F,
                                       h1, H_F, b1 + (size_t)k * H_F, N_NODES, IN_F, stream);
        // MLP layer 2: h2 = h1 @ W2[k] + b2[k]
        launch_gemm<false, true, false>(h1, H_F, W2 + (size_t)k * H_F * H_F, H_F,
                                        h2, H_F, b2 + (size_t)k * H_F, N_NODES, H_F, stream);
        // relation accumulation: hop k contributes window slot (k-r) of relation r
        int rlo = (k - 2 < 0) ? 0 : (k - 2);
        int rhi = (k < R_REL - 1) ? k : (R_REL - 1);
        for (int r = rlo; r <= rhi; ++r) {
            const float* Bp = Wr + ((size_t)r * (3 * H_F) + (size_t)(k - r) * H_F) * H_F;
            float* Cp = out + (size_t)r * H_F;
            if (k == r) {
                // first window slot: fresh write + bias br[r]
                launch_gemm<false, true, false>(h2, H_F, Bp, H_F, Cp, OUT_W,
                                                br + (size_t)r * H_F, N_NODES, H_F, stream);
            } else if (k == r + 2) {
                // last window slot: accumulate + relu
                launch_gemm<true, false, true>(h2, H_F, Bp, H_F, Cp, OUT_W,
                                               nullptr, N_NODES, H_F, stream);
            } else {
                launch_gemm<true, false, false>(h2, H_F, Bp, H_F, Cp, OUT_W,
                                                nullptr, N_NODES, H_F, stream);
            }
        }
        // propagate: x_{k+1} = A_hat @ x_k
        if (k < K_HOPS - 1) {
            float* xn = bufs[k & 1];
            spmm_init<<<(N_NODES * (IN_F / 4) + 255) / 256, 256, 0, stream>>>(
                (const float4*)xcur, dinv, (float4*)xn);
            spmm_edges<<<(E_EDGES * (IN_F / 4) + 255) / 256, 256, 0, stream>>>(
                (const float4*)xcur, ew, row, col, xn);
            xcur = xn;
        }
    }
}

// Round 2
// 5676.706 us; speedup vs baseline: 3.6673x; 3.6673x over previous
//
#include <hip/hip_runtime.h>

#define N_NODES 100000
#define E_EDGES 1600000
#define IN_F 128
#define H_F 256
#define K_HOPS 7
#define R_REL 5
#define OUT_W (R_REL * H_F)  // 1280

// ---------------- small utility kernels ----------------

__global__ void zero_int(int* __restrict__ p, int n) {
    int t = blockIdx.x * blockDim.x + threadIdx.x;
    if (t < n) p[t] = 0;
}

__global__ void deg_count(const int* __restrict__ row, int* __restrict__ deg) {
    int e = blockIdx.x * blockDim.x + threadIdx.x;
    if (e < E_EDGES) atomicAdd(&deg[row[e]], 1);
}

__global__ void dinv_compute(const int* __restrict__ deg, float* __restrict__ dinv) {
    int i = blockIdx.x * blockDim.x + threadIdx.x;
    if (i < N_NODES) dinv[i] = rsqrtf((float)(deg[i] + 1));  // +1 self loop; always > 0
}

// exclusive scan of deg[N] -> rowptr[N+1], single 1024-thread block, wave-shuffle scans
__global__ __launch_bounds__(1024) void exscan_rowptr(const int* __restrict__ deg,
                                                      int* __restrict__ rowptr) {
    __shared__ int wsum[16];
    __shared__ int carry_s;
    const int t = threadIdx.x, lane = t & 63, wv = t >> 6;
    if (t == 0) carry_s = 0;
    __syncthreads();
    for (int base = 0; base < N_NODES; base += 1024) {
        int i = base + t;
        int v = (i < N_NODES) ? deg[i] : 0;
        int x = v;
#pragma unroll
        for (int off = 1; off < 64; off <<= 1) {
            int n = __shfl_up(x, off, 64);
            if (lane >= off) x += n;
        }
        if (lane == 63) wsum[wv] = x;
        __syncthreads();
        if (wv == 0 && lane < 16) {
            int s = wsum[lane];
#pragma unroll
            for (int off = 1; off < 16; off <<= 1) {
                int n = __shfl_up(s, off, 64);
                if (lane >= off) s += n;
            }
            wsum[lane] = s;  // inclusive over waves
        }
        __syncthreads();
        int wbase = (wv == 0) ? 0 : wsum[wv - 1];
        if (i < N_NODES) rowptr[i] = carry_s + wbase + x - v;
        __syncthreads();
        if (t == 1023) carry_s += wsum[15];
        __syncthreads();
    }
    if (threadIdx.x == 0) rowptr[N_NODES] = carry_s;
}

// counting-sort edges into CSR order; weight computed inline
__global__ void csr_scatter(const int* __restrict__ row, const int* __restrict__ col,
                            const float* __restrict__ dinv, const int* __restrict__ rowptr,
                            int* __restrict__ cursor, int* __restrict__ cols2,
                            float* __restrict__ w2) {
    int e = blockIdx.x * blockDim.x + threadIdx.x;
    if (e >= E_EDGES) return;
    int r = row[e], c = col[e];
    int pos = rowptr[r] + atomicAdd(&cursor[r], 1);
    cols2[pos] = c;
    w2[pos] = dinv[r] * dinv[c];
}

// y[i] = dinv[i]^2 * x[i] + sum_j w[j] * x[cols[j]]   (one wave per row, float2/lane)
__global__ __launch_bounds__(256) void spmm_csr(
    const float2* __restrict__ x, const int* __restrict__ rowptr,
    const int* __restrict__ cols, const float* __restrict__ w,
    const float* __restrict__ dinv, float2* __restrict__ y) {
    const int wave = threadIdx.x >> 6, lane = threadIdx.x & 63;
    const int i = blockIdx.x * 4 + wave;
    if (i >= N_NODES) return;
    const float d = dinv[i];
    float2 xv = x[(size_t)i * 64 + lane];
    float2 acc;
    acc.x = d * d * xv.x;
    acc.y = d * d * xv.y;
    int j = rowptr[i];
    const int e = rowptr[i + 1];
    for (; j + 1 < e; j += 2) {
        int c0 = cols[j], c1 = cols[j + 1];
        float w0 = w[j], w1 = w[j + 1];
        float2 v0 = x[(size_t)c0 * 64 + lane];
        float2 v1 = x[(size_t)c1 * 64 + lane];
        acc.x += w0 * v0.x + w1 * v1.x;
        acc.y += w0 * v0.y + w1 * v1.y;
    }
    if (j < e) {
        int c0 = cols[j];
        float w0 = w[j];
        float2 v0 = x[(size_t)c0 * 64 + lane];
        acc.x += w0 * v0.x;
        acc.y += w0 * v0.y;
    }
    y[(size_t)i * 64 + lane] = acc;
}

// ---------------- fp32 tiled GEMM ----------------
// C[M,256] (+)= A[M,K] @ B[K,256] (+ bias) (+ relu)
// BM=128, BN=64, BK=16; 256 threads; 8x4 micro-tile per thread.

#define BM 128
#define BN 64
#define BK 16

template <bool ACCUM, bool BIAS, bool RELU>
__global__ __launch_bounds__(256) void gemm_f32(
    const float* __restrict__ A, int lda,
    const float* __restrict__ B, int ldb,
    float* __restrict__ C, int ldc,
    const float* __restrict__ bias,
    int M, int K)
{
    __shared__ float As[BK][BM];  // transposed: As[k][m]
    __shared__ float Bs[BK][BN];

    const int tid = threadIdx.x;
    const int tx = tid & 15;   // col group (4 cols)
    const int ty = tid >> 4;   // row group (8 rows)
    const int m0 = blockIdx.y * BM;
    const int n0 = blockIdx.x * BN;

    float acc[8][4];
#pragma unroll
    for (int i = 0; i < 8; ++i)
#pragma unroll
        for (int j = 0; j < 4; ++j) acc[i][j] = 0.f;

    for (int k0 = 0; k0 < K; k0 += BK) {
        // A tile: 128x16 = 512 float4, 2 per thread, store transposed
#pragma unroll
        for (int l = 0; l < 2; ++l) {
            int fid = tid + l * 256;
            int r = fid >> 2, c4 = fid & 3;
            float4 v = make_float4(0.f, 0.f, 0.f, 0.f);
            int m = m0 + r;
            if (m < M) v = *(const float4*)(A + (long)m * lda + k0 + c4 * 4);
            As[c4 * 4 + 0][r] = v.x;
            As[c4 * 4 + 1][r] = v.y;
            As[c4 * 4 + 2][r] = v.z;
            As[c4 * 4 + 3][r] = v.w;
        }
        // B tile: 16x64 = 256 float4, 1 per thread
        {
            int r = tid >> 4, c4 = tid & 15;
            float4 v = *(const float4*)(B + (long)(k0 + r) * ldb + n0 + c4 * 4);
            *(float4*)&Bs[r][c4 * 4] = v;
        }
        __syncthreads();
#pragma unroll
        for (int kk = 0; kk < BK; ++kk) {
            float4 b4 = *(const float4*)&Bs[kk][tx * 4];
            float4 a0 = *(const float4*)&As[kk][ty * 8];
            float4 a1 = *(const float4*)&As[kk][ty * 8 + 4];
            float a[8] = {a0.x, a0.y, a0.z, a0.w, a1.x, a1.y, a1.z, a1.w};
            float b[4] = {b4.x, b4.y, b4.z, b4.w};
#pragma unroll
            for (int i = 0; i < 8; ++i)
#pragma unroll
                for (int j = 0; j < 4; ++j)
                    acc[i][j] = fmaf(a[i], b[j], acc[i][j]);
        }
        __syncthreads();
    }

#pragma unroll
    for (int i = 0; i < 8; ++i) {
        int m = m0 + ty * 8 + i;
        if (m < M) {
            float* cp = C + (long)m * ldc + n0 + tx * 4;
#pragma unroll
            for (int j = 0; j < 4; ++j) {
                float v = acc[i][j];
                if (BIAS) v += bias[n0 + tx * 4 + j];
                if (ACCUM) v += cp[j];
                if (RELU) v = fmaxf(v, 0.f);
                cp[j] = v;
            }
        }
    }
}

template <bool ACC, bool BI, bool RE>
static void launch_gemm(const float* A, int lda, const float* B, int ldb,
                        float* C, int ldc, const float* bias, int M, int K,
                        hipStream_t s) {
    dim3 grid(H_F / BN, (M + BM - 1) / BM);  // N is always 256 wide here
    gemm_f32<ACC, BI, RE><<<grid, 256, 0, s>>>(A, lda, B, ldb, C, ldc, bias, M, K);
}

// ---------------- driver ----------------

extern "C" void kernel_launch(void* const* d_in, const int* in_sizes, int n_in,
                              void* d_out, int out_size, void* d_ws, size_t ws_size,
                              hipStream_t stream) {
    const float* features = (const float*)d_in[0];
    const float* W1 = (const float*)d_in[1];
    const float* b1 = (const float*)d_in[2];
    const float* W2 = (const float*)d_in[3];
    const float* b2 = (const float*)d_in[4];
    const float* Wr = (const float*)d_in[5];
    const float* br = (const float*)d_in[6];
    const int* row = (const int*)d_in[7];
    const int* col = (const int*)d_in[8];
    float* out = (float*)d_out;

    // workspace layout (bytes)
    char* ws = (char*)d_ws;
    int* deg = (int*)ws;                              // [0, 400K)  also reused as cursor
    int* rowptr = (int*)(ws + (512 << 10));           // [512K, 912K+4)
    float* dinv = (float*)(ws + (1 << 20));           // [1M, 1.4M)
    int* cols2 = (int*)(ws + (2ull << 20));           // [2M, 8.4M)
    float* w2 = (float*)(ws + (9ull << 20));          // [9M, 15.4M)
    float* xa = (float*)(ws + (16ull << 20));         // [16M, +51.2M)
    float* xb = xa + (size_t)N_NODES * IN_F;
    float* h1 = xb + (size_t)N_NODES * IN_F;          // N*256
    float* h2 = h1 + (size_t)N_NODES * H_F;           // N*256

    // ---- adjacency normalization + CSR build ----
    zero_int<<<(N_NODES + 255) / 256, 256, 0, stream>>>(deg, N_NODES);
    deg_count<<<(E_EDGES + 255) / 256, 256, 0, stream>>>(row, deg);
    dinv_compute<<<(N_NODES + 255) / 256, 256, 0, stream>>>(deg, dinv);
    exscan_rowptr<<<1, 1024, 0, stream>>>(deg, rowptr);
    zero_int<<<(N_NODES + 255) / 256, 256, 0, stream>>>(deg, N_NODES);  // deg -> cursor
    csr_scatter<<<(E_EDGES + 255) / 256, 256, 0, stream>>>(row, col, dinv, rowptr,
                                                           deg, cols2, w2);

    // ---- hop loop: MLP(k) -> accumulate into relation windows; then propagate ----
    const float* xcur = features;
    float* bufs[2] = {xa, xb};
    for (int k = 0; k < K_HOPS; ++k) {
        // MLP layer 1: h1 = relu(x @ W1[k] + b1[k])
        launch_gemm<false, true, true>(xcur, IN_F, W1 + (size_t)k * IN_F * H_F, H_F,
                                       h1, H_F, b1 + (size_t)k * H_F, N_NODES, IN_F, stream);
        // MLP layer 2: h2 = h1 @ W2[k] + b2[k]
        launch_gemm<false, true, false>(h1, H_F, W2 + (size_t)k * H_F * H_F, H_F,
                                        h2, H_F, b2 + (size_t)k * H_F, N_NODES, H_F, stream);
        // relation accumulation: hop k contributes window slot (k-r) of relation r
        int rlo = (k - 2 < 0) ? 0 : (k - 2);
        int rhi = (k < R_REL - 1) ? k : (R_REL - 1);
        for (int r = rlo; r <= rhi; ++r) {
            const float* Bp = Wr + ((size_t)r * (3 * H_F) + (size_t)(k - r) * H_F) * H_F;
            float* Cp = out + (size_t)r * H_F;
            if (k == r) {
                // first window slot: fresh write + bias br[r]
                launch_gemm<false, true, false>(h2, H_F, Bp, H_F, Cp, OUT_W,
                                                br + (size_t)r * H_F, N_NODES, H_F, stream);
            } else if (k == r + 2) {
                // last window slot: accumulate + relu
                launch_gemm<true, false, true>(h2, H_F, Bp, H_F, Cp, OUT_W,
                                               nullptr, N_NODES, H_F, stream);
            } else {
                launch_gemm<true, false, false>(h2, H_F, Bp, H_F, Cp, OUT_W,
                                                nullptr, N_NODES, H_F, stream);
            }
        }
        // propagate: x_{k+1} = A_hat @ x_k
        if (k < K_HOPS - 1) {
            float* xn = bufs[k & 1];
            spmm_csr<<<(N_NODES + 3) / 4, 256, 0, stream>>>(
                (const float2*)xcur, rowptr, cols2, w2, dinv, (float2*)xn);
            xcur = xn;
        }
    }
}

// Round 3
// 2935.149 us; speedup vs baseline: 7.0927x; 1.9340x over previous
//
#include <hip/hip_runtime.h>

#define N_NODES 100000
#define E_EDGES 1600000
#define IN_F 128
#define H_F 256
#define K_HOPS 7
#define R_REL 5
#define OUT_W (R_REL * H_F)  // 1280

typedef __attribute__((ext_vector_type(8))) short short8;
typedef __attribute__((ext_vector_type(4))) float f32x4;

// ---------------- small utility kernels ----------------

__global__ void zero_int(int* __restrict__ p, int n) {
    int t = blockIdx.x * blockDim.x + threadIdx.x;
    if (t < n) p[t] = 0;
}

__global__ void deg_count(const int* __restrict__ row, int* __restrict__ deg) {
    int e = blockIdx.x * blockDim.x + threadIdx.x;
    if (e < E_EDGES) atomicAdd(&deg[row[e]], 1);
}

__global__ void dinv_compute(const int* __restrict__ deg, float* __restrict__ dinv) {
    int i = blockIdx.x * blockDim.x + threadIdx.x;
    if (i < N_NODES) dinv[i] = rsqrtf((float)(deg[i] + 1));
}

// exclusive scan of deg[N] -> rowptr[N+1], single 1024-thread block
__global__ __launch_bounds__(1024) void exscan_rowptr(const int* __restrict__ deg,
                                                      int* __restrict__ rowptr) {
    __shared__ int wsum[16];
    __shared__ int carry_s;
    const int t = threadIdx.x, lane = t & 63, wv = t >> 6;
    if (t == 0) carry_s = 0;
    __syncthreads();
    for (int base = 0; base < N_NODES; base += 1024) {
        int i = base + t;
        int v = (i < N_NODES) ? deg[i] : 0;
        int x = v;
#pragma unroll
        for (int off = 1; off < 64; off <<= 1) {
            int n = __shfl_up(x, off, 64);
            if (lane >= off) x += n;
        }
        if (lane == 63) wsum[wv] = x;
        __syncthreads();
        if (wv == 0 && lane < 16) {
            int s = wsum[lane];
#pragma unroll
            for (int off = 1; off < 16; off <<= 1) {
                int n = __shfl_up(s, off, 64);
                if (lane >= off) s += n;
            }
            wsum[lane] = s;
        }
        __syncthreads();
        int wbase = (wv == 0) ? 0 : wsum[wv - 1];
        if (i < N_NODES) rowptr[i] = carry_s + wbase + x - v;
        __syncthreads();
        if (t == 1023) carry_s += wsum[15];
        __syncthreads();
    }
    if (threadIdx.x == 0) rowptr[N_NODES] = carry_s;
}

__global__ void csr_scatter(const int* __restrict__ row, const int* __restrict__ col,
                            const float* __restrict__ dinv, const int* __restrict__ rowptr,
                            int* __restrict__ cursor, int* __restrict__ cols2,
                            float* __restrict__ w2) {
    int e = blockIdx.x * blockDim.x + threadIdx.x;
    if (e >= E_EDGES) return;
    int r = row[e], c = col[e];
    int pos = rowptr[r] + atomicAdd(&cursor[r], 1);
    cols2[pos] = c;
    w2[pos] = dinv[r] * dinv[c];
}

// y[i] = dinv[i]^2 * x[i] + sum_j w[j] * x[cols[j]]   (one wave per row, float2/lane)
__global__ __launch_bounds__(256) void spmm_csr(
    const float2* __restrict__ x, const int* __restrict__ rowptr,
    const int* __restrict__ cols, const float* __restrict__ w,
    const float* __restrict__ dinv, float2* __restrict__ y) {
    const int wave = threadIdx.x >> 6, lane = threadIdx.x & 63;
    const int i = blockIdx.x * 4 + wave;
    if (i >= N_NODES) return;
    const float d = dinv[i];
    float2 xv = x[(size_t)i * 64 + lane];
    float2 acc;
    acc.x = d * d * xv.x;
    acc.y = d * d * xv.y;
    int j = rowptr[i];
    const int e = rowptr[i + 1];
    for (; j + 1 < e; j += 2) {
        int c0 = cols[j], c1 = cols[j + 1];
        float w0 = w[j], w1 = w[j + 1];
        float2 v0 = x[(size_t)c0 * 64 + lane];
        float2 v1 = x[(size_t)c1 * 64 + lane];
        acc.x += w0 * v0.x + w1 * v1.x;
        acc.y += w0 * v0.y + w1 * v1.y;
    }
    if (j < e) {
        int c0 = cols[j];
        float w0 = w[j];
        float2 v0 = x[(size_t)c0 * 64 + lane];
        acc.x += w0 * v0.x;
        acc.y += w0 * v0.y;
    }
    y[(size_t)i * 64 + lane] = acc;
}

// ---------------- bf16 split helpers ----------------

__device__ __forceinline__ void f2bf_split(float v, short& h, short& l) {
    unsigned u = __float_as_uint(v);
    unsigned hb = (u + 0x7FFFu + ((u >> 16) & 1u)) >> 16;  // RN-to-even bf16
    float fh = __uint_as_float(hb << 16);
    float r = v - fh;
    unsigned u2 = __float_as_uint(r);
    unsigned lb = (u2 + 0x7FFFu + ((u2 >> 16) & 1u)) >> 16;
    h = (short)(unsigned short)hb;
    l = (short)(unsigned short)lb;
}

// weight transpose+split: in [cnt][Kd][256] fp32 -> out_hi/lo [cnt][256][Kd] bf16
// grid (Kd/32, 8, cnt), block (32,8)
__global__ void transpose_convert(const float* __restrict__ in, short* __restrict__ oh,
                                  short* __restrict__ ol, int Kd) {
    __shared__ float t[32][33];
    const int i0 = blockIdx.x * 32, n0 = blockIdx.y * 32, c = blockIdx.z;
    const int tx = threadIdx.x, ty = threadIdx.y;
    const float* ip = in + (size_t)c * Kd * 256;
#pragma unroll
    for (int j = 0; j < 4; ++j)
        t[ty + 8 * j][tx] = ip[(size_t)(i0 + ty + 8 * j) * 256 + n0 + tx];
    __syncthreads();
    size_t base = (size_t)c * 256 * Kd;
#pragma unroll
    for (int j = 0; j < 4; ++j) {
        float v = t[tx][ty + 8 * j];
        short hb, lb;
        f2bf_split(v, hb, lb);
        size_t o = base + (size_t)(n0 + ty + 8 * j) * Kd + i0 + tx;
        oh[o] = hb;
        ol[o] = lb;
    }
}

// ---------------- split-bf16 MFMA GEMM ----------------
// C[M,256-slice] = A[M,K] @ B[K,256] (+bias) (+relu) (+accum)
// block tile 128x128, 4 waves (2M x 2N), wave tile 64x64, BK=32
// LDS rows: 40 bf16 elems (80 B) -> 16B-aligned, 2-way bank aliasing (free)
// MODE: 0 = bias, 1 = bias+relu, 2 = accum, 3 = accum+relu

#define LROW 40

template <int MODE>
__global__ __launch_bounds__(256, 2) void gemm_split(
    const float* __restrict__ A, int lda, long hopStride,
    const short* __restrict__ BTh, const short* __restrict__ BTl, int ldb, int Kd,
    float* __restrict__ C, int ldc, const float* __restrict__ bias, int M)
{
    __shared__ short lds_buf[4 * 128 * LROW];
    short* Ah = lds_buf;
    short* Al = lds_buf + 128 * LROW;
    short* Bh = lds_buf + 2 * 128 * LROW;
    short* Bl = lds_buf + 3 * 128 * LROW;

    const int tid = threadIdx.x;
    const int lane = tid & 63, wave = tid >> 6;
    const int wm = wave & 1, wn = wave >> 1;
    const int fr = lane & 15, fg = lane >> 4;
    const int m0 = blockIdx.y * 128;
    const int n0 = blockIdx.x * 128;

    // staging coords: each thread stages 16 contiguous k-elems of one row
    const int sr = tid >> 1;             // 0..127
    const int sc = (tid & 1) * 16;       // 0 or 16
    const bool avalid = (m0 + sr) < M;
    const int arow = avalid ? (m0 + sr) : (M - 1);

    f32x4 ga[4];
    short8 gbh[2], gbl[2];

    // prologue load k0=0
    {
        const float* ap = A + (size_t)arow * lda + sc;
        const short* bph = BTh + (size_t)(n0 + sr) * ldb + sc;
        const short* bpl = BTl + (size_t)(n0 + sr) * ldb + sc;
#pragma unroll
        for (int l = 0; l < 4; ++l) ga[l] = *(const f32x4*)(ap + 4 * l);
        gbh[0] = *(const short8*)bph;  gbh[1] = *(const short8*)(bph + 8);
        gbl[0] = *(const short8*)bpl;  gbl[1] = *(const short8*)(bpl + 8);
    }

    f32x4 acc[4][4];
#pragma unroll
    for (int i = 0; i < 4; ++i)
#pragma unroll
        for (int j = 0; j < 4; ++j) acc[i][j] = (f32x4)0.f;

    const int nk = Kd / 32;
    for (int kk = 0; kk < nk; ++kk) {
        __syncthreads();  // previous iter's fragment reads complete
        // convert + write staged tile to LDS
        {
            short8 vh[2], vl[2];
#pragma unroll
            for (int l = 0; l < 4; ++l) {
                f32x4 v = ga[l];
                if (!avalid) v = (f32x4)0.f;
#pragma unroll
                for (int e = 0; e < 4; ++e) {
                    short hb, lb;
                    f2bf_split(v[e], hb, lb);
                    vh[l >> 1][(l & 1) * 4 + e] = hb;
                    vl[l >> 1][(l & 1) * 4 + e] = lb;
                }
            }
            *(short8*)(Ah + sr * LROW + sc)     = vh[0];
            *(short8*)(Ah + sr * LROW + sc + 8) = vh[1];
            *(short8*)(Al + sr * LROW + sc)     = vl[0];
            *(short8*)(Al + sr * LROW + sc + 8) = vl[1];
            *(short8*)(Bh + sr * LROW + sc)     = gbh[0];
            *(short8*)(Bh + sr * LROW + sc + 8) = gbh[1];
            *(short8*)(Bl + sr * LROW + sc)     = gbl[0];
            *(short8*)(Bl + sr * LROW + sc + 8) = gbl[1];
        }
        __syncthreads();

        // prefetch next k-step (overlaps with MFMA cluster below)
        if (kk + 1 < nk) {
            int k0 = (kk + 1) * 32;
            const float* ap = A + (size_t)(k0 >> 8) * hopStride + (k0 & 255)
                              + (size_t)arow * lda + sc;
            const short* bph = BTh + (size_t)(n0 + sr) * ldb + k0 + sc;
            const short* bpl = BTl + (size_t)(n0 + sr) * ldb + k0 + sc;
#pragma unroll
            for (int l = 0; l < 4; ++l) ga[l] = *(const f32x4*)(ap + 4 * l);
            gbh[0] = *(const short8*)bph;  gbh[1] = *(const short8*)(bph + 8);
            gbl[0] = *(const short8*)bpl;  gbl[1] = *(const short8*)(bpl + 8);
        }

        // fragment reads
        short8 afh[4], afl[4], bfh[4], bfl[4];
#pragma unroll
        for (int mf = 0; mf < 4; ++mf) {
            int r = wm * 64 + mf * 16 + fr;
            afh[mf] = *(const short8*)(Ah + r * LROW + fg * 8);
            afl[mf] = *(const short8*)(Al + r * LROW + fg * 8);
        }
#pragma unroll
        for (int nf = 0; nf < 4; ++nf) {
            int r = wn * 64 + nf * 16 + fr;
            bfh[nf] = *(const short8*)(Bh + r * LROW + fg * 8);
            bfl[nf] = *(const short8*)(Bl + r * LROW + fg * 8);
        }
        // 48 MFMAs: hi*hi + hi*lo + lo*hi
#pragma unroll
        for (int mf = 0; mf < 4; ++mf)
#pragma unroll
            for (int nf = 0; nf < 4; ++nf) {
                acc[mf][nf] = __builtin_amdgcn_mfma_f32_16x16x32_bf16(
                    afh[mf], bfh[nf], acc[mf][nf], 0, 0, 0);
                acc[mf][nf] = __builtin_amdgcn_mfma_f32_16x16x32_bf16(
                    afh[mf], bfl[nf], acc[mf][nf], 0, 0, 0);
                acc[mf][nf] = __builtin_amdgcn_mfma_f32_16x16x32_bf16(
                    afl[mf], bfh[nf], acc[mf][nf], 0, 0, 0);
            }
    }

    // epilogue: C/D layout col=lane&15, row=(lane>>4)*4+reg
#pragma unroll
    for (int nf = 0; nf < 4; ++nf) {
        int colg = n0 + wn * 64 + nf * 16 + fr;
        float bv = (MODE <= 1) ? bias[colg] : 0.f;
#pragma unroll
        for (int mf = 0; mf < 4; ++mf) {
            int rowbase = m0 + wm * 64 + mf * 16 + fg * 4;
#pragma unroll
            for (int j = 0; j < 4; ++j) {
                int rowg = rowbase + j;
                if (rowg < M) {
                    float* cp = C + (size_t)rowg * ldc + colg;
                    float v = acc[mf][nf][j] + bv;
                    if (MODE >= 2) v += *cp;
                    if (MODE & 1) v = fmaxf(v, 0.f);
                    *cp = v;
                }
            }
        }
    }
}

template <int MODE>
static void launch_gemm(const float* A, int lda, long hopStride,
                        const short* BTh, const short* BTl, int ldb, int Kd,
                        float* C, int ldc, const float* bias, int M, hipStream_t s) {
    dim3 grid(2, (M + 127) / 128);
    gemm_split<MODE><<<grid, 256, 0, s>>>(A, lda, hopStride, BTh, BTl, ldb, Kd,
                                          C, ldc, bias, M);
}

// ---------------- driver ----------------

extern "C" void kernel_launch(void* const* d_in, const int* in_sizes, int n_in,
                              void* d_out, int out_size, void* d_ws, size_t ws_size,
                              hipStream_t stream) {
    const float* features = (const float*)d_in[0];
    const float* W1 = (const float*)d_in[1];
    const float* b1 = (const float*)d_in[2];
    const float* W2 = (const float*)d_in[3];
    const float* b2 = (const float*)d_in[4];
    const float* Wr = (const float*)d_in[5];
    const float* br = (const float*)d_in[6];
    const int* row = (const int*)d_in[7];
    const int* col = (const int*)d_in[8];
    float* out = (float*)d_out;

    // workspace layout (byte offsets)
    char* ws = (char*)d_ws;
    int* deg = (int*)ws;                                 // 400KB (also cursor)
    int* rowptr = (int*)(ws + (1ull << 20));             // 400KB+4
    float* dinv = (float*)(ws + (2ull << 20));           // 400KB
    int* cols2 = (int*)(ws + (4ull << 20));              // 6.4MB
    float* w2 = (float*)(ws + (11ull << 20));            // 6.4MB
    short* w1h = (short*)(ws + (18ull << 20));           // 459KB
    short* w1l = (short*)(ws + (19ull << 20));
    short* w2h = (short*)(ws + (20ull << 20));           // 918KB
    short* w2l = (short*)(ws + (21ull << 20));
    short* wrh = (short*)(ws + (22ull << 20));           // 1.97MB
    short* wrl = (short*)(ws + (24ull << 20));
    float* xa = (float*)(ws + (28ull << 20));            // 51.2MB
    float* xb = (float*)(ws + (80ull << 20));            // 51.2MB
    float* h1 = (float*)(ws + (132ull << 20));           // 102.4MB
    float* h2 = (float*)(ws + (236ull << 20));           // windowed: 716.8MB; fallback: 102.4MB

    const bool windowed = ws_size >= (1000ull << 20);

    // ---- adjacency normalization + CSR build ----
    zero_int<<<(N_NODES + 255) / 256, 256, 0, stream>>>(deg, N_NODES);
    deg_count<<<(E_EDGES + 255) / 256, 256, 0, stream>>>(row, deg);
    dinv_compute<<<(N_NODES + 255) / 256, 256, 0, stream>>>(deg, dinv);
    exscan_rowptr<<<1, 1024, 0, stream>>>(deg, rowptr);
    zero_int<<<(N_NODES + 255) / 256, 256, 0, stream>>>(deg, N_NODES);
    csr_scatter<<<(E_EDGES + 255) / 256, 256, 0, stream>>>(row, col, dinv, rowptr,
                                                           deg, cols2, w2);

    // ---- weight transpose + bf16 split ----
    dim3 tb(32, 8);
    transpose_convert<<<dim3(IN_F / 32, 8, K_HOPS), tb, 0, stream>>>(W1, w1h, w1l, IN_F);
    transpose_convert<<<dim3(H_F / 32, 8, K_HOPS), tb, 0, stream>>>(W2, w2h, w2l, H_F);
    transpose_convert<<<dim3(768 / 32, 8, R_REL), tb, 0, stream>>>(Wr, wrh, wrl, 768);

    // ---- hop loop ----
    const float* xcur = features;
    float* bufs[2] = {xa, xb};
    for (int k = 0; k < K_HOPS; ++k) {
        // MLP1: h1 = relu(x @ W1[k] + b1[k])
        launch_gemm<1>(xcur, IN_F, 0, w1h + (size_t)k * 256 * IN_F,
                       w1l + (size_t)k * 256 * IN_F, IN_F, IN_F,
                       h1, H_F, b1 + (size_t)k * H_F, N_NODES, stream);
        // MLP2: h2[k] = h1 @ W2[k] + b2[k]
        float* h2dst = windowed ? (h2 + (size_t)k * N_NODES * H_F) : h2;
        launch_gemm<0>(h1, H_F, 0, w2h + (size_t)k * 256 * H_F,
                       w2l + (size_t)k * 256 * H_F, H_F, H_F,
                       h2dst, H_F, b2 + (size_t)k * H_F, N_NODES, stream);

        if (!windowed) {
            // per-hop relation accumulation
            int rlo = (k - 2 < 0) ? 0 : (k - 2);
            int rhi = (k < R_REL - 1) ? k : (R_REL - 1);
            for (int r = rlo; r <= rhi; ++r) {
                const short* Bh = wrh + (size_t)r * 256 * 768 + (size_t)(k - r) * 256;
                const short* Bl = wrl + (size_t)r * 256 * 768 + (size_t)(k - r) * 256;
                float* Cp = out + (size_t)r * H_F;
                if (k == r)
                    launch_gemm<0>(h2, H_F, 0, Bh, Bl, 768, H_F, Cp, OUT_W,
                                   br + (size_t)r * H_F, N_NODES, stream);
                else if (k == r + 2)
                    launch_gemm<3>(h2, H_F, 0, Bh, Bl, 768, H_F, Cp, OUT_W,
                                   nullptr, N_NODES, stream);
                else
                    launch_gemm<2>(h2, H_F, 0, Bh, Bl, 768, H_F, Cp, OUT_W,
                                   nullptr, N_NODES, stream);
            }
        }

        if (k < K_HOPS - 1) {
            float* xn = bufs[k & 1];
            spmm_csr<<<(N_NODES + 3) / 4, 256, 0, stream>>>(
                (const float2*)xcur, rowptr, cols2, w2, dinv, (float2*)xn);
            xcur = xn;
        }
    }

    if (windowed) {
        // 5 relation GEMMs, K=768 over the hop window
        for (int r = 0; r < R_REL; ++r) {
            launch_gemm<1>(h2 + (size_t)r * N_NODES * H_F, H_F, (long)N_NODES * H_F,
                           wrh + (size_t)r * 256 * 768, wrl + (size_t)r * 256 * 768,
                           768, 768, out + (size_t)r * H_F, OUT_W,
                           br + (size_t)r * H_F, N_NODES, stream);
        }
    }
}

// Round 4
// 2450.464 us; speedup vs baseline: 8.4955x; 1.1978x over previous
//
#include <hip/hip_runtime.h>

#define N_NODES 100000
#define E_EDGES 1600000
#define IN_F 128
#define H_F 256
#define K_HOPS 7
#define R_REL 5
#define OUT_W (R_REL * H_F)  // 1280

typedef __attribute__((ext_vector_type(8))) short short8;
typedef __attribute__((ext_vector_type(4))) float f32x4;

// ---------------- small utility kernels ----------------

__global__ void zero_int(int* __restrict__ p, int n) {
    int t = blockIdx.x * blockDim.x + threadIdx.x;
    if (t < n) p[t] = 0;
}

__global__ void deg_count(const int* __restrict__ row, int* __restrict__ deg) {
    int e = blockIdx.x * blockDim.x + threadIdx.x;
    if (e < E_EDGES) atomicAdd(&deg[row[e]], 1);
}

__global__ void dinv_compute(const int* __restrict__ deg, float* __restrict__ dinv) {
    int i = blockIdx.x * blockDim.x + threadIdx.x;
    if (i < N_NODES) dinv[i] = rsqrtf((float)(deg[i] + 1));
}

// exclusive scan of deg[N] -> rowptr[N+1], single 1024-thread block
__global__ __launch_bounds__(1024) void exscan_rowptr(const int* __restrict__ deg,
                                                      int* __restrict__ rowptr) {
    __shared__ int wsum[16];
    __shared__ int carry_s;
    const int t = threadIdx.x, lane = t & 63, wv = t >> 6;
    if (t == 0) carry_s = 0;
    __syncthreads();
    for (int base = 0; base < N_NODES; base += 1024) {
        int i = base + t;
        int v = (i < N_NODES) ? deg[i] : 0;
        int x = v;
#pragma unroll
        for (int off = 1; off < 64; off <<= 1) {
            int n = __shfl_up(x, off, 64);
            if (lane >= off) x += n;
        }
        if (lane == 63) wsum[wv] = x;
        __syncthreads();
        if (wv == 0 && lane < 16) {
            int s = wsum[lane];
#pragma unroll
            for (int off = 1; off < 16; off <<= 1) {
                int n = __shfl_up(s, off, 64);
                if (lane >= off) s += n;
            }
            wsum[lane] = s;
        }
        __syncthreads();
        int wbase = (wv == 0) ? 0 : wsum[wv - 1];
        if (i < N_NODES) rowptr[i] = carry_s + wbase + x - v;
        __syncthreads();
        if (t == 1023) carry_s += wsum[15];
        __syncthreads();
    }
    if (threadIdx.x == 0) rowptr[N_NODES] = carry_s;
}

__global__ void csr_scatter(const int* __restrict__ row, const int* __restrict__ col,
                            const float* __restrict__ dinv, const int* __restrict__ rowptr,
                            int* __restrict__ cursor, int* __restrict__ cols2,
                            float* __restrict__ ew) {
    int e = blockIdx.x * blockDim.x + threadIdx.x;
    if (e >= E_EDGES) return;
    int r = row[e], c = col[e];
    int pos = rowptr[r] + atomicAdd(&cursor[r], 1);
    cols2[pos] = c;
    ew[pos] = dinv[r] * dinv[c];
}

// y[i] = dinv[i]^2 * x[i] + sum_j w[j] * x[cols[j]]   (one wave per row, float2/lane)
__global__ __launch_bounds__(256) void spmm_csr(
    const float2* __restrict__ x, const int* __restrict__ rowptr,
    const int* __restrict__ cols, const float* __restrict__ w,
    const float* __restrict__ dinv, float2* __restrict__ y) {
    const int wave = threadIdx.x >> 6, lane = threadIdx.x & 63;
    const int i = blockIdx.x * 4 + wave;
    if (i >= N_NODES) return;
    const float d = dinv[i];
    float2 xv = x[(size_t)i * 64 + lane];
    float2 acc;
    acc.x = d * d * xv.x;
    acc.y = d * d * xv.y;
    int j = rowptr[i];
    const int e = rowptr[i + 1];
    for (; j + 3 < e; j += 4) {
        int c0 = cols[j], c1 = cols[j + 1], c2 = cols[j + 2], c3 = cols[j + 3];
        float w0 = w[j], w1 = w[j + 1], w2 = w[j + 2], w3 = w[j + 3];
        float2 v0 = x[(size_t)c0 * 64 + lane];
        float2 v1 = x[(size_t)c1 * 64 + lane];
        float2 v2 = x[(size_t)c2 * 64 + lane];
        float2 v3 = x[(size_t)c3 * 64 + lane];
        acc.x += w0 * v0.x + w1 * v1.x + w2 * v2.x + w3 * v3.x;
        acc.y += w0 * v0.y + w1 * v1.y + w2 * v2.y + w3 * v3.y;
    }
    for (; j < e; ++j) {
        int c0 = cols[j];
        float w0 = w[j];
        float2 v0 = x[(size_t)c0 * 64 + lane];
        acc.x += w0 * v0.x;
        acc.y += w0 * v0.y;
    }
    y[(size_t)i * 64 + lane] = acc;
}

// ---------------- weight-fusion precompute ----------------
// Wc[z=r*3+d] = W2[r+d] @ WrS[r,d]   ([256j][256g] = [256j][256h] @ [256h][256g])
__global__ __launch_bounds__(256) void wc_compute(const float* __restrict__ W2,
                                                  const float* __restrict__ Wr,
                                                  float* __restrict__ Wc) {
    const int z = blockIdx.x, j = blockIdx.y, g = threadIdx.x;
    const int r = z / 3, d = z % 3, hop = r + d;
    const float* a = W2 + (size_t)hop * H_F * H_F + (size_t)j * H_F;
    const float* b = Wr + ((size_t)r * 768 + (size_t)d * H_F) * H_F + g;
    float acc = 0.f;
#pragma unroll 4
    for (int h = 0; h < H_F; ++h) acc += a[h] * b[(size_t)h * H_F];
    Wc[(size_t)z * H_F * H_F + (size_t)j * H_F + g] = acc;
}

// bc[r] = br[r] + sum_{d,h} b2[r+d][h] * WrS[r,d][h][:]
__global__ __launch_bounds__(256) void bc_compute(const float* __restrict__ b2,
                                                  const float* __restrict__ Wr,
                                                  const float* __restrict__ br,
                                                  float* __restrict__ bc) {
    const int r = blockIdx.x, g = threadIdx.x;
    float acc = br[(size_t)r * H_F + g];
    for (int t = 0; t < 3 * H_F; ++t) {
        float bv = b2[(size_t)(r + t / H_F) * H_F + (t % H_F)];
        acc += bv * Wr[((size_t)r * 768 + t) * H_F + g];
    }
    bc[(size_t)r * H_F + g] = acc;
}

// ---------------- bf16 split helpers ----------------

__device__ __forceinline__ void f2bf_split(float v, short& h, short& l) {
    unsigned u = __float_as_uint(v);
    unsigned hb = (u + 0x7FFFu + ((u >> 16) & 1u)) >> 16;  // RN-to-even bf16
    float fh = __uint_as_float(hb << 16);
    float r = v - fh;
    unsigned u2 = __float_as_uint(r);
    unsigned lb = (u2 + 0x7FFFu + ((u2 >> 16) & 1u)) >> 16;
    h = (short)(unsigned short)hb;
    l = (short)(unsigned short)lb;
}

// weight transpose+split: in [z][Kd][256] fp32 -> BT groups: out group (z/grp) is
// [256][grp*Kd] bf16, z%grp selects the Kd-column slab.  grid (Kd/32, 8, nz), block (32,8)
__global__ void transpose_convert(const float* __restrict__ in, short* __restrict__ oh,
                                  short* __restrict__ ol, int Kd, int grp) {
    __shared__ float t[32][33];
    const int i0 = blockIdx.x * 32, n0 = blockIdx.y * 32, z = blockIdx.z;
    const int tx = threadIdx.x, ty = threadIdx.y;
    const int outLd = grp * Kd;
    const float* ip = in + (size_t)z * Kd * 256;
#pragma unroll
    for (int j = 0; j < 4; ++j)
        t[ty + 8 * j][tx] = ip[(size_t)(i0 + ty + 8 * j) * 256 + n0 + tx];
    __syncthreads();
    size_t base = (size_t)(z / grp) * 256 * outLd + (size_t)(z % grp) * Kd;
#pragma unroll
    for (int j = 0; j < 4; ++j) {
        float v = t[tx][ty + 8 * j];
        short hb, lb;
        f2bf_split(v, hb, lb);
        size_t o = base + (size_t)(n0 + ty + 8 * j) * outLd + i0 + tx;
        oh[o] = hb;
        ol[o] = lb;
    }
}

// ---------------- split-bf16 MFMA GEMM ----------------
// C[M,256-slice] = A[M,K] @ B[K,256] (+bias) (+relu) (+accum)
// block tile 128x128, 4 waves (2M x 2N), wave tile 64x64, BK=32
// A may span hops: element (m, k) at A + (k>>8)*hopStride + (k&255) + m*lda
// MODE: 0 = bias, 1 = bias+relu, 2 = accum, 3 = accum+relu

#define LROW 40

template <int MODE>
__global__ __launch_bounds__(256, 2) void gemm_split(
    const float* __restrict__ A, int lda, long hopStride,
    const short* __restrict__ BTh, const short* __restrict__ BTl, int ldb, int Kd,
    float* __restrict__ C, int ldc, const float* __restrict__ bias, int M)
{
    __shared__ short lds_buf[4 * 128 * LROW];
    short* Ah = lds_buf;
    short* Al = lds_buf + 128 * LROW;
    short* Bh = lds_buf + 2 * 128 * LROW;
    short* Bl = lds_buf + 3 * 128 * LROW;

    const int tid = threadIdx.x;
    const int lane = tid & 63, wave = tid >> 6;
    const int wm = wave & 1, wn = wave >> 1;
    const int fr = lane & 15, fg = lane >> 4;
    const int m0 = blockIdx.y * 128;
    const int n0 = blockIdx.x * 128;

    const int sr = tid >> 1;
    const int sc = (tid & 1) * 16;
    const bool avalid = (m0 + sr) < M;
    const int arow = avalid ? (m0 + sr) : (M - 1);

    f32x4 ga[4];
    short8 gbh[2], gbl[2];

    {
        const float* ap = A + (size_t)arow * lda + sc;
        const short* bph = BTh + (size_t)(n0 + sr) * ldb + sc;
        const short* bpl = BTl + (size_t)(n0 + sr) * ldb + sc;
#pragma unroll
        for (int l = 0; l < 4; ++l) ga[l] = *(const f32x4*)(ap + 4 * l);
        gbh[0] = *(const short8*)bph;  gbh[1] = *(const short8*)(bph + 8);
        gbl[0] = *(const short8*)bpl;  gbl[1] = *(const short8*)(bpl + 8);
    }

    f32x4 acc[4][4];
#pragma unroll
    for (int i = 0; i < 4; ++i)
#pragma unroll
        for (int j = 0; j < 4; ++j) acc[i][j] = (f32x4)0.f;

    const int nk = Kd / 32;
    for (int kk = 0; kk < nk; ++kk) {
        __syncthreads();
        {
            short8 vh[2], vl[2];
#pragma unroll
            for (int l = 0; l < 4; ++l) {
                f32x4 v = ga[l];
                if (!avalid) v = (f32x4)0.f;
#pragma unroll
                for (int e = 0; e < 4; ++e) {
                    short hb, lb;
                    f2bf_split(v[e], hb, lb);
                    vh[l >> 1][(l & 1) * 4 + e] = hb;
                    vl[l >> 1][(l & 1) * 4 + e] = lb;
                }
            }
            *(short8*)(Ah + sr * LROW + sc)     = vh[0];
            *(short8*)(Ah + sr * LROW + sc + 8) = vh[1];
            *(short8*)(Al + sr * LROW + sc)     = vl[0];
            *(short8*)(Al + sr * LROW + sc + 8) = vl[1];
            *(short8*)(Bh + sr * LROW + sc)     = gbh[0];
            *(short8*)(Bh + sr * LROW + sc + 8) = gbh[1];
            *(short8*)(Bl + sr * LROW + sc)     = gbl[0];
            *(short8*)(Bl + sr * LROW + sc + 8) = gbl[1];
        }
        __syncthreads();

        if (kk + 1 < nk) {
            int k0 = (kk + 1) * 32;
            const float* ap = A + (size_t)(k0 >> 8) * hopStride + (k0 & 255)
                              + (size_t)arow * lda + sc;
            const short* bph = BTh + (size_t)(n0 + sr) * ldb + k0 + sc;
            const short* bpl = BTl + (size_t)(n0 + sr) * ldb + k0 + sc;
#pragma unroll
            for (int l = 0; l < 4; ++l) ga[l] = *(const f32x4*)(ap + 4 * l);
            gbh[0] = *(const short8*)bph;  gbh[1] = *(const short8*)(bph + 8);
            gbl[0] = *(const short8*)bpl;  gbl[1] = *(const short8*)(bpl + 8);
        }

        short8 afh[4], afl[4], bfh[4], bfl[4];
#pragma unroll
        for (int mf = 0; mf < 4; ++mf) {
            int r = wm * 64 + mf * 16 + fr;
            afh[mf] = *(const short8*)(Ah + r * LROW + fg * 8);
            afl[mf] = *(const short8*)(Al + r * LROW + fg * 8);
        }
#pragma unroll
        for (int nf = 0; nf < 4; ++nf) {
            int r = wn * 64 + nf * 16 + fr;
            bfh[nf] = *(const short8*)(Bh + r * LROW + fg * 8);
            bfl[nf] = *(const short8*)(Bl + r * LROW + fg * 8);
        }
#pragma unroll
        for (int mf = 0; mf < 4; ++mf)
#pragma unroll
            for (int nf = 0; nf < 4; ++nf) {
                acc[mf][nf] = __builtin_amdgcn_mfma_f32_16x16x32_bf16(
                    afh[mf], bfh[nf], acc[mf][nf], 0, 0, 0);
                acc[mf][nf] = __builtin_amdgcn_mfma_f32_16x16x32_bf16(
                    afh[mf], bfl[nf], acc[mf][nf], 0, 0, 0);
                acc[mf][nf] = __builtin_amdgcn_mfma_f32_16x16x32_bf16(
                    afl[mf], bfh[nf], acc[mf][nf], 0, 0, 0);
            }
    }

#pragma unroll
    for (int nf = 0; nf < 4; ++nf) {
        int colg = n0 + wn * 64 + nf * 16 + fr;
        float bv = (MODE <= 1) ? bias[colg] : 0.f;
#pragma unroll
        for (int mf = 0; mf < 4; ++mf) {
            int rowbase = m0 + wm * 64 + mf * 16 + fg * 4;
#pragma unroll
            for (int j = 0; j < 4; ++j) {
                int rowg = rowbase + j;
                if (rowg < M) {
                    float* cp = C + (size_t)rowg * ldc + colg;
                    float v = acc[mf][nf][j] + bv;
                    if (MODE >= 2) v += *cp;
                    if (MODE & 1) v = fmaxf(v, 0.f);
                    *cp = v;
                }
            }
        }
    }
}

template <int MODE>
static void launch_gemm(const float* A, int lda, long hopStride,
                        const short* BTh, const short* BTl, int ldb, int Kd,
                        float* C, int ldc, const float* bias, int M, hipStream_t s) {
    dim3 grid(2, (M + 127) / 128);
    gemm_split<MODE><<<grid, 256, 0, s>>>(A, lda, hopStride, BTh, BTl, ldb, Kd,
                                          C, ldc, bias, M);
}

// ---------------- driver ----------------

extern "C" void kernel_launch(void* const* d_in, const int* in_sizes, int n_in,
                              void* d_out, int out_size, void* d_ws, size_t ws_size,
                              hipStream_t stream) {
    const float* features = (const float*)d_in[0];
    const float* W1 = (const float*)d_in[1];
    const float* b1 = (const float*)d_in[2];
    const float* W2 = (const float*)d_in[3];
    const float* b2 = (const float*)d_in[4];
    const float* Wr = (const float*)d_in[5];
    const float* br = (const float*)d_in[6];
    const int* row = (const int*)d_in[7];
    const int* col = (const int*)d_in[8];
    float* out = (float*)d_out;

    // workspace layout (byte offsets)
    char* ws = (char*)d_ws;
    int* deg = (int*)ws;                                 // 400KB (also cursor)
    int* rowptr = (int*)(ws + (1ull << 20));
    float* dinv = (float*)(ws + (2ull << 20));
    int* cols2 = (int*)(ws + (4ull << 20));              // 6.4MB
    float* ew = (float*)(ws + (11ull << 20));            // 6.4MB
    short* w1h = (short*)(ws + (18ull << 20));           // 459KB
    short* w1l = (short*)(ws + (19ull << 20));
    float* wc32 = (float*)(ws + (20ull << 20));          // 3.93MB
    short* wch = (short*)(ws + (24ull << 20));           // 1.97MB
    short* wcl = (short*)(ws + (26ull << 20));
    float* bc = (float*)(ws + (28ull << 20));            // 5KB
    float* xa = (float*)(ws + (32ull << 20));            // 51.2MB
    float* xb = (float*)(ws + (96ull << 20));            // 51.2MB
    float* h1 = (float*)(ws + (160ull << 20));           // windowed: 716.8MB; else 102.4MB

    const bool windowed = ws_size >= (1000ull << 20);

    // ---- adjacency normalization + CSR build ----
    zero_int<<<(N_NODES + 255) / 256, 256, 0, stream>>>(deg, N_NODES);
    deg_count<<<(E_EDGES + 255) / 256, 256, 0, stream>>>(row, deg);
    dinv_compute<<<(N_NODES + 255) / 256, 256, 0, stream>>>(deg, dinv);
    exscan_rowptr<<<1, 1024, 0, stream>>>(deg, rowptr);
    zero_int<<<(N_NODES + 255) / 256, 256, 0, stream>>>(deg, N_NODES);
    csr_scatter<<<(E_EDGES + 255) / 256, 256, 0, stream>>>(row, col, dinv, rowptr,
                                                           deg, cols2, ew);

    // ---- weight fusion: Wc = W2 @ WrS, bc = br + b2 @ WrS ----
    wc_compute<<<dim3(15, H_F), 256, 0, stream>>>(W2, Wr, wc32);
    bc_compute<<<R_REL, 256, 0, stream>>>(b2, Wr, br, bc);

    // ---- weight transpose + bf16 split ----
    dim3 tb(32, 8);
    transpose_convert<<<dim3(IN_F / 32, 8, K_HOPS), tb, 0, stream>>>(W1, w1h, w1l, IN_F, 1);
    transpose_convert<<<dim3(H_F / 32, 8, 15), tb, 0, stream>>>(wc32, wch, wcl, H_F, 3);

    // ---- hop loop: MLP1 only; then propagate ----
    const float* xcur = features;
    float* bufs[2] = {xa, xb};
    for (int k = 0; k < K_HOPS; ++k) {
        float* h1dst = windowed ? (h1 + (size_t)k * N_NODES * H_F) : h1;
        launch_gemm<1>(xcur, IN_F, 0, w1h + (size_t)k * 256 * IN_F,
                       w1l + (size_t)k * 256 * IN_F, IN_F, IN_F,
                       h1dst, H_F, b1 + (size_t)k * H_F, N_NODES, stream);

        if (!windowed) {
            // per-hop relation accumulation: out[r] (+)= h1 @ Wc[r][k-r]
            int rlo = (k - 2 < 0) ? 0 : (k - 2);
            int rhi = (k < R_REL - 1) ? k : (R_REL - 1);
            for (int r = rlo; r <= rhi; ++r) {
                int d = k - r;
                const short* Bh = wch + (size_t)r * 256 * 768 + (size_t)d * H_F;
                const short* Bl = wcl + (size_t)r * 256 * 768 + (size_t)d * H_F;
                float* Cp = out + (size_t)r * H_F;
                if (k == r)
                    launch_gemm<0>(h1, H_F, 0, Bh, Bl, 768, H_F, Cp, OUT_W,
                                   bc + (size_t)r * H_F, N_NODES, stream);
                else if (k == r + 2)
                    launch_gemm<3>(h1, H_F, 0, Bh, Bl, 768, H_F, Cp, OUT_W,
                                   nullptr, N_NODES, stream);
                else
                    launch_gemm<2>(h1, H_F, 0, Bh, Bl, 768, H_F, Cp, OUT_W,
                                   nullptr, N_NODES, stream);
            }
        }

        if (k < K_HOPS - 1) {
            float* xn = bufs[k & 1];
            spmm_csr<<<(N_NODES + 3) / 4, 256, 0, stream>>>(
                (const float2*)xcur, rowptr, cols2, ew, dinv, (float2*)xn);
            xcur = xn;
        }
    }

    if (windowed) {
        // 5 relation GEMMs, K=768 over the h1 hop window
        for (int r = 0; r < R_REL; ++r) {
            launch_gemm<1>(h1 + (size_t)r * N_NODES * H_F, H_F, (long)N_NODES * H_F,
                           wch + (size_t)r * 256 * 768, wcl + (size_t)r * 256 * 768,
                           768, 768, out + (size_t)r * H_F, OUT_W,
                           bc + (size_t)r * H_F, N_NODES, stream);
        }
    }
}